// Round 8
// baseline (357.033 us; speedup 1.0000x reference)
//
#include <hip/hip_runtime.h>
#include <hip/hip_bf16.h>

// Problem constants (B=8,S=2048,H=16,D=80 -> DM=1280, M=B*S=16384)
#define M_TOT   16384
#define DMODEL  1280
#define NHEAD   16
#define DHEAD   80
#define NTC     5          // 1280 / 256 column tiles per matrix
#define BK      64
#define NKT     (DMODEL / BK)   // 20 K-tiles

typedef __attribute__((ext_vector_type(8))) __bf16 bf16x8;
typedef __attribute__((ext_vector_type(4))) float  f32x4;

__device__ __forceinline__ void gload16(const void* g, void* l) {
  __builtin_amdgcn_global_load_lds(
      (const __attribute__((address_space(1))) void*)g,
      (__attribute__((address_space(3))) void*)l, 16, 0, 0);
}

__device__ __forceinline__ float bf2f(unsigned short u) {
  return __uint_as_float((unsigned)u << 16);
}

// ---------------- fp32 -> bf16 convert, vectorized ----------------
__global__ __launch_bounds__(256) void cvt_bf16_kernel(
    const float* __restrict__ x, __hip_bfloat16* __restrict__ y, int n4) {
  int i = blockIdx.x * 256 + threadIdx.x;
  if (i >= n4) return;
  float4 v = ((const float4*)x)[i];
  union { ushort4 u; __hip_bfloat16 h[4]; } o;
  o.h[0] = __float2bfloat16(v.x);
  o.h[1] = __float2bfloat16(v.y);
  o.h[2] = __float2bfloat16(v.z);
  o.h[3] = __float2bfloat16(v.w);
  ((ushort4*)y)[i] = o.u;
}

// ---------------- W [K][N] fp32  ->  Wt [N][K] bf16 ----------------
// For Wp (z==3), per_dim_scale is folded in: Wt[n][k] = Wp[k][n]*pds[k%80]
// (pds scales the attention output dim k before the projection; pds==1.0 in
// the given inputs so numerics are unchanged).
__global__ __launch_bounds__(256) void transpose_cvt_kernel(
    const float* __restrict__ W0, const float* __restrict__ W1,
    const float* __restrict__ W2, const float* __restrict__ W3,
    const float* __restrict__ pds,
    __hip_bfloat16* __restrict__ T0, __hip_bfloat16* __restrict__ T1,
    __hip_bfloat16* __restrict__ T2, __hip_bfloat16* __restrict__ T3) {
  const float* W = blockIdx.z == 0 ? W0 : blockIdx.z == 1 ? W1
                 : blockIdx.z == 2 ? W2 : W3;
  __hip_bfloat16* T = blockIdx.z == 0 ? T0 : blockIdx.z == 1 ? T1
                    : blockIdx.z == 2 ? T2 : T3;
  __shared__ float tile[32][33];
  int bx = blockIdx.x * 32, by = blockIdx.y * 32;
  int tx = threadIdx.x, ty = threadIdx.y;   // block (32,8)
  for (int j = 0; j < 32; j += 8)
    tile[ty + j][tx] = W[(size_t)(by + ty + j) * DMODEL + bx + tx];
  __syncthreads();
  // store col index k' = by+tx (fixed per thread)
  const float scale = (blockIdx.z == 3) ? pds[(by + tx) % DHEAD] : 1.0f;
  for (int j = 0; j < 32; j += 8)
    T[(size_t)(bx + ty + j) * DMODEL + by + tx] =
        __float2bfloat16(tile[tx][ty + j] * scale);
}

// 16-MFMA cluster: acc[MB..MB+3][0..3] += AF[j] x BF[n]
#define MFMA16(AF, BF, MB)                                                   \
  do {                                                                       \
    _Pragma("unroll")                                                        \
    for (int j_ = 0; j_ < 4; ++j_) {                                         \
      _Pragma("unroll")                                                      \
      for (int n_ = 0; n_ < 4; ++n_)                                         \
        acc[(MB) + j_][n_] = __builtin_amdgcn_mfma_f32_16x16x32_bf16(        \
            AF[j_], BF[n_], acc[(MB) + j_][n_], 0, 0, 0);                    \
    }                                                                        \
  } while (0)

// ---------------- QKV GEMM: 256x256, 8 waves (schedule frozen from R6) ----
// R8: bijective chunked XCD swizzle (T1). hw id b -> l = (b%8)*(nwg/8)+b/8,
// tiles y-major: each XCD's 32 concurrent blocks share ONE B panel (640 KB,
// L2-resident) -> the 2-phase-cover B staging loads become L2 hits.
template <bool OUT_BF16>
__global__ __launch_bounds__(512, 2) void gemm_bt_kernel(
    const __hip_bfloat16* __restrict__ A,   // [M][K]
    const __hip_bfloat16* __restrict__ Bt0, // [N][K] (= W^T)
    const __hip_bfloat16* __restrict__ Bt1,
    const __hip_bfloat16* __restrict__ Bt2,
    const float* __restrict__ bias0, const float* __restrict__ bias1,
    const float* __restrict__ bias2,
    void* __restrict__ C0, void* __restrict__ C1, void* __restrict__ C2) {
  // ---- XCD-chunked swizzle: nwg = 64*15 = 960 = 8*120 ----
  const int b   = blockIdx.x + gridDim.x * blockIdx.y;  // hw linear id
  const int l   = (b & 7) * 120 + (b >> 3);             // bijective remap
  const int xt  = l & 63;                                // 64 row tiles
  const int yy  = l >> 6;                                // 15 col tiles
  const int mat   = yy / NTC;
  const int ntile = yy % NTC;
  const __hip_bfloat16* Bt = mat == 0 ? Bt0 : mat == 1 ? Bt1 : Bt2;
  const float* bias        = mat == 0 ? bias0 : mat == 1 ? bias1 : bias2;
  void* C                  = mat == 0 ? C0 : mat == 1 ? C1 : C2;

  const int bm = xt * 256;
  const int bn = ntile * 256;

  // A: 2 bufs x 2 ks x 16KB = 64KB at 0; B: same at 65536. Total 128KB.
  __shared__ __align__(16) char SLDS[131072];

  const int tid  = threadIdx.x;
  const int lane = tid & 63;
  const int wid  = tid >> 6;            // 0..7
  const int wm   = (wid >> 2) * 128;    // wave row offset: 0,128
  const int wn   = (wid & 3) * 64;      // wave col offset: 0,64,128,192
  const int lrow = lane & 15;
  const int l4   = lane >> 4;           // 0..3

  const int rsub  = lane >> 2;                        // 0..15
  const int cswz  = (lane & 3) ^ ((rsub >> 1) & 3);   // global chunk low bits
  const char* gsrc[2][2][2];
#pragma unroll
  for (int i = 0; i < 2; ++i) {
    const int rA = bm + wid * 32 + i * 16 + rsub;
    const int rB = bn + wid * 32 + i * 16 + rsub;
#pragma unroll
    for (int s = 0; s < 2; ++s) {
      gsrc[0][i][s] = (const char*)A  + (size_t)rA * (DMODEL * 2) + s * 64 + cswz * 16;
      gsrc[1][i][s] = (const char*)Bt + (size_t)rB * (DMODEL * 2) + s * 64 + cswz * 16;
    }
  }

  auto issueGroup = [&](int M, int s, int nbuf, size_t koff) {
    char* d = SLDS + M * 65536 + nbuf * 32768 + s * 16384 + wid * 2048;
    gload16(gsrc[M][0][s] + koff, d);
    gload16(gsrc[M][1][s] + koff, d + 1024);
  };

  f32x4 acc[8][4];
#pragma unroll
  for (int i = 0; i < 8; ++i)
#pragma unroll
    for (int j = 0; j < 4; ++j) acc[i][j] = (f32x4){0.f, 0.f, 0.f, 0.f};

  const int swz  = ((l4 ^ ((lrow >> 1) & 3)) << 4);
  const int aOff = (wm + lrow) * 64 + swz;           // within A region
  const int bOff = 65536 + (wn + lrow) * 64 + swz;   // within B region

  issueGroup(0, 0, 0, 0);   // A-ks0
  issueGroup(1, 0, 0, 0);   // B-ks0
  issueGroup(0, 1, 0, 0);   // A-ks1
  issueGroup(1, 1, 0, 0);   // B-ks1
  asm volatile("s_waitcnt vmcnt(4)" ::: "memory");
  __builtin_amdgcn_s_barrier();

  bf16x8 aFa[4], aFb[4], aFc[4], aFd[4], bF0[4], bF1[4];
#pragma unroll
  for (int j = 0; j < 4; ++j) aFa[j] = *(const bf16x8*)(const void*)(SLDS + aOff + j * 1024);
#pragma unroll
  for (int n = 0; n < 4; ++n) bF0[n] = *(const bf16x8*)(const void*)(SLDS + bOff + n * 1024);
  __builtin_amdgcn_sched_barrier(0);

  for (int t = 0; t < NKT; ++t) {
    const int buf = t & 1, nbuf = buf ^ 1;
    const int b0 = buf << 15;
    const int n0 = nbuf << 15;
    const size_t koff = (size_t)(t + 1) * (BK * 2);
    const bool pf = (t + 1 < NKT);

    // ---------- phase 0 ----------
    __builtin_amdgcn_s_barrier();
#pragma unroll
    for (int j = 0; j < 4; ++j)
      aFb[j] = *(const bf16x8*)(const void*)(SLDS + b0 + aOff + (4 + j) * 1024);
    if (pf) issueGroup(0, 0, nbuf, koff);
    __builtin_amdgcn_sched_barrier(0);
    __builtin_amdgcn_s_setprio(1);
    MFMA16(aFa, bF0, 0);
    __builtin_amdgcn_s_setprio(0);
    __builtin_amdgcn_sched_barrier(0);

    // ---------- phase 1 ----------
    if (pf) asm volatile("s_waitcnt vmcnt(2)" ::: "memory");
    else    asm volatile("s_waitcnt vmcnt(0)" ::: "memory");
    __builtin_amdgcn_s_barrier();
#pragma unroll
    for (int j = 0; j < 4; ++j)
      aFc[j] = *(const bf16x8*)(const void*)(SLDS + b0 + 16384 + aOff + j * 1024);
#pragma unroll
    for (int n = 0; n < 4; ++n)
      bF1[n] = *(const bf16x8*)(const void*)(SLDS + b0 + 16384 + bOff + n * 1024);
    if (pf) issueGroup(1, 0, nbuf, koff);
    __builtin_amdgcn_sched_barrier(0);
    __builtin_amdgcn_s_setprio(1);
    MFMA16(aFb, bF0, 4);
    __builtin_amdgcn_s_setprio(0);
    __builtin_amdgcn_sched_barrier(0);

    // ---------- phase 2 ----------
    __builtin_amdgcn_s_barrier();
#pragma unroll
    for (int j = 0; j < 4; ++j)
      aFd[j] = *(const bf16x8*)(const void*)(SLDS + b0 + 16384 + aOff + (4 + j) * 1024);
    if (pf) issueGroup(0, 1, nbuf, koff);
    __builtin_amdgcn_sched_barrier(0);
    __builtin_amdgcn_s_setprio(1);
    MFMA16(aFc, bF1, 0);
    __builtin_amdgcn_s_setprio(0);
    __builtin_amdgcn_sched_barrier(0);

    // ---------- phase 3 ----------
    if (pf) asm volatile("s_waitcnt vmcnt(2)" ::: "memory");
    __builtin_amdgcn_s_barrier();
    if (pf) {
#pragma unroll
      for (int j = 0; j < 4; ++j)
        aFa[j] = *(const bf16x8*)(const void*)(SLDS + n0 + aOff + j * 1024);
#pragma unroll
      for (int n = 0; n < 4; ++n)
        bF0[n] = *(const bf16x8*)(const void*)(SLDS + n0 + bOff + n * 1024);
      issueGroup(1, 1, nbuf, koff);
    }
    __builtin_amdgcn_sched_barrier(0);
    __builtin_amdgcn_s_setprio(1);
    MFMA16(aFd, bF1, 4);
    __builtin_amdgcn_s_setprio(0);
    __builtin_amdgcn_sched_barrier(0);
  }

  const int rbase = l4 * 4;
#pragma unroll
  for (int mi = 0; mi < 8; ++mi) {
#pragma unroll
    for (int ni = 0; ni < 4; ++ni) {
      const int col = bn + wn + ni * 16 + lrow;
      const float b2 = bias[col];
#pragma unroll
      for (int r = 0; r < 4; ++r) {
        const int row = bm + wm + mi * 16 + rbase + r;
        const float val = acc[mi][ni][r] + b2;
        if (OUT_BF16)
          ((__hip_bfloat16*)C)[(size_t)row * DMODEL + col] = __float2bfloat16(val);
        else
          ((float*)C)[(size_t)row * DMODEL + col] = val;
      }
    }
  }
}

// ---------------- proj GEMM: 128x128 tile, 4 waves, 2 blocks/CU ----------------
// R8: same chunked XCD swizzle (nwg = 128*10 = 1280 = 8*160).
__global__ __launch_bounds__(256, 2) void gemm_bt128_kernel(
    const __hip_bfloat16* __restrict__ A,   // [M][K]
    const __hip_bfloat16* __restrict__ Bt,  // [N][K]
    const float* __restrict__ bias,
    float* __restrict__ C) {
  const int b  = blockIdx.x + gridDim.x * blockIdx.y;
  const int l  = (b & 7) * 160 + (b >> 3);
  const int bm = (l & 127) * 128;   // 128 row tiles
  const int bn = (l >> 7) * 128;    // 10 col tiles

  // A: 2 bufs x 2 ks x 8KB = 32KB at 0; B: same at 32768. Total 64KB.
  __shared__ __align__(16) char SLDS[65536];

  const int tid  = threadIdx.x;
  const int lane = tid & 63;
  const int wid  = tid >> 6;            // 0..3
  const int wm   = (wid >> 1) * 64;     // wave row offset: 0,64
  const int wn   = (wid & 1) * 64;      // wave col offset: 0,64
  const int lrow = lane & 15;
  const int l4   = lane >> 4;

  const int rsub  = lane >> 2;
  const int cswz  = (lane & 3) ^ ((rsub >> 1) & 3);
  const char* gsrc[2][2][2];
#pragma unroll
  for (int i = 0; i < 2; ++i) {
    const int rA = bm + wid * 32 + i * 16 + rsub;
    const int rB = bn + wid * 32 + i * 16 + rsub;
#pragma unroll
    for (int s = 0; s < 2; ++s) {
      gsrc[0][i][s] = (const char*)A  + (size_t)rA * (DMODEL * 2) + s * 64 + cswz * 16;
      gsrc[1][i][s] = (const char*)Bt + (size_t)rB * (DMODEL * 2) + s * 64 + cswz * 16;
    }
  }

  auto issueGroup = [&](int M, int s, int nbuf, size_t koff) {
    char* d = SLDS + M * 32768 + nbuf * 16384 + s * 8192 + wid * 2048;
    gload16(gsrc[M][0][s] + koff, d);
    gload16(gsrc[M][1][s] + koff, d + 1024);
  };

  f32x4 acc[4][4];
#pragma unroll
  for (int i = 0; i < 4; ++i)
#pragma unroll
    for (int j = 0; j < 4; ++j) acc[i][j] = (f32x4){0.f, 0.f, 0.f, 0.f};

  const int swz  = ((l4 ^ ((lrow >> 1) & 3)) << 4);
  const int aOff = (wm + lrow) * 64 + swz;
  const int bOff = 32768 + (wn + lrow) * 64 + swz;

  issueGroup(0, 0, 0, 0);   // A-ks0
  issueGroup(1, 0, 0, 0);   // B-ks0
  issueGroup(0, 1, 0, 0);   // A-ks1
  issueGroup(1, 1, 0, 0);   // B-ks1

  for (int t = 0; t < NKT; ++t) {
    const int buf = t & 1, nbuf = buf ^ 1;
    const int b0 = buf << 14;            // 16KB per buf within each region
    const size_t koff = (size_t)(t + 1) * (BK * 2);
    const bool pf = (t + 1 < NKT);

    // ---------- phase 0: ks0 ----------
    asm volatile("s_waitcnt vmcnt(4)" ::: "memory");  // A-ks0,B-ks0(t) landed
    __builtin_amdgcn_s_barrier();
    bf16x8 aF[4], bF[4];
#pragma unroll
    for (int j = 0; j < 4; ++j)
      aF[j] = *(const bf16x8*)(const void*)(SLDS + b0 + aOff + j * 1024);
#pragma unroll
    for (int n = 0; n < 4; ++n)
      bF[n] = *(const bf16x8*)(const void*)(SLDS + b0 + bOff + n * 1024);
    if (pf) { issueGroup(0, 0, nbuf, koff); issueGroup(1, 0, nbuf, koff); }
    __builtin_amdgcn_sched_barrier(0);
    __builtin_amdgcn_s_setprio(1);
    MFMA16(aF, bF, 0);
    __builtin_amdgcn_s_setprio(0);
    __builtin_amdgcn_sched_barrier(0);

    // ---------- phase 1: ks1 ----------
    if (pf) asm volatile("s_waitcnt vmcnt(4)" ::: "memory");  // A-ks1,B-ks1(t)
    else    asm volatile("s_waitcnt vmcnt(0)" ::: "memory");
    __builtin_amdgcn_s_barrier();
#pragma unroll
    for (int j = 0; j < 4; ++j)
      aF[j] = *(const bf16x8*)(const void*)(SLDS + b0 + 8192 + aOff + j * 1024);
#pragma unroll
    for (int n = 0; n < 4; ++n)
      bF[n] = *(const bf16x8*)(const void*)(SLDS + b0 + 8192 + bOff + n * 1024);
    if (pf) { issueGroup(0, 1, nbuf, koff); issueGroup(1, 1, nbuf, koff); }
    __builtin_amdgcn_sched_barrier(0);
    __builtin_amdgcn_s_setprio(1);
    MFMA16(aF, bF, 0);
    __builtin_amdgcn_s_setprio(0);
    __builtin_amdgcn_sched_barrier(0);
  }

  const int rbase = l4 * 4;
#pragma unroll
  for (int mi = 0; mi < 4; ++mi) {
#pragma unroll
    for (int ni = 0; ni < 4; ++ni) {
      const int col = bn + wn + ni * 16 + lrow;
      const float bb = bias[col];
#pragma unroll
      for (int r = 0; r < 4; ++r) {
        const int row = bm + wm + mi * 16 + rbase + r;
        C[(size_t)row * DMODEL + col] = acc[mi][ni][r] + bb;
      }
    }
  }
}

// ---------------- per-position head-mixing attention ----------------
// scores[h][t] = (q[h,:] . k[t,:]) / sqrt(80) over heads (16x16), softmax
// over t, out[h][d] = sum_t p[h][t] v[t][d]. (per_dim_scale folded into Wp.)
__global__ __launch_bounds__(256) void attn_kernel(
    const __hip_bfloat16* __restrict__ q, const __hip_bfloat16* __restrict__ k,
    const __hip_bfloat16* __restrict__ v,
    __hip_bfloat16* __restrict__ out) {
  const size_t base = (size_t)blockIdx.x * DMODEL;
  __shared__ float qs[16][81], ks[16][81], vs[16][81];
  __shared__ float ps[16][17];
  const int tid = threadIdx.x;

  // 480 chunk loads (3 matrices x 160 bf16x8 chunks)
  for (int c = tid; c < 480; c += 256) {
    int matid = c / 160, idx = c - matid * 160;
    int h = idx / 10, d0 = (idx - h * 10) * 8;
    const __hip_bfloat16* src = matid == 0 ? q : matid == 1 ? k : v;
    union { bf16x8 v8; unsigned short u[8]; } uu;
    uu.v8 = *(const bf16x8*)(const void*)(src + base + (size_t)idx * 8);
    float* dst = (matid == 0 ? &qs[0][0] : matid == 1 ? &ks[0][0] : &vs[0][0]) +
                 h * 81 + d0;
#pragma unroll
    for (int j = 0; j < 8; ++j) dst[j] = bf2f(uu.u[j]);
  }
  __syncthreads();

  const int h = tid >> 4, t = tid & 15;
  float s = 0.f;
#pragma unroll
  for (int d = 0; d < DHEAD; ++d) s += qs[h][d] * ks[t][d];
  s *= 0.11180339887498948f;  // 1/sqrt(80)

  float m = s;
#pragma unroll
  for (int off = 8; off; off >>= 1) m = fmaxf(m, __shfl_xor(m, off, 16));
  float e = expf(s - m);
  float sum = e;
#pragma unroll
  for (int off = 8; off; off >>= 1) sum += __shfl_xor(sum, off, 16);
  ps[h][t] = e / sum;
  __syncthreads();

  // PV: 256 threads x 5 outputs (head hh = tid>>4, d = (tid&15)*5 .. +4)
  {
    const int hh   = tid >> 4;
    const int dloc = (tid & 15) * 5;
    float o[5];
#pragma unroll
    for (int j = 0; j < 5; ++j) o[j] = 0.f;
#pragma unroll
    for (int tt = 0; tt < 16; ++tt) {
      const float p = ps[hh][tt];
#pragma unroll
      for (int j = 0; j < 5; ++j) o[j] += p * vs[tt][dloc + j];
    }
    __hip_bfloat16* ob = out + base + (size_t)hh * DHEAD + dloc;
#pragma unroll
    for (int j = 0; j < 5; ++j) ob[j] = __float2bfloat16(o[j]);
  }
}

// ---------------- launch ----------------
extern "C" void kernel_launch(void* const* d_in, const int* in_sizes, int n_in,
                              void* d_out, int out_size, void* d_ws, size_t ws_size,
                              hipStream_t stream) {
  const float* x   = (const float*)d_in[0];
  const float* Wq  = (const float*)d_in[1];
  const float* bq  = (const float*)d_in[2];
  const float* Wk  = (const float*)d_in[3];
  const float* bk  = (const float*)d_in[4];
  const float* Wv  = (const float*)d_in[5];
  const float* bv  = (const float*)d_in[6];
  const float* Wp  = (const float*)d_in[7];
  const float* bp  = (const float*)d_in[8];
  const float* pds = (const float*)d_in[9];
  float* out = (float*)d_out;

  char* ws = (char*)d_ws;
  const size_t ACT = (size_t)M_TOT * DMODEL * 2;      // 41,943,040 B
  const size_t WT  = (size_t)DMODEL * DMODEL * 2;     //  3,276,800 B
  __hip_bfloat16* xbf = (__hip_bfloat16*)(ws);
  __hip_bfloat16* qbf = (__hip_bfloat16*)(ws + ACT);
  __hip_bfloat16* kbf = (__hip_bfloat16*)(ws + 2 * ACT);
  __hip_bfloat16* vbf = (__hip_bfloat16*)(ws + 3 * ACT);
  __hip_bfloat16* wtq = (__hip_bfloat16*)(ws + 4 * ACT);
  __hip_bfloat16* wtk = (__hip_bfloat16*)(ws + 4 * ACT + WT);
  __hip_bfloat16* wtv = (__hip_bfloat16*)(ws + 4 * ACT + 2 * WT);
  __hip_bfloat16* wtp = (__hip_bfloat16*)(ws + 4 * ACT + 3 * WT);
  __hip_bfloat16* attnbf = xbf;  // alias: x is dead after the QKV GEMM

  // 1) x -> bf16
  {
    int n4 = (M_TOT * DMODEL) / 4;  // 5,242,880
    cvt_bf16_kernel<<<n4 / 256, 256, 0, stream>>>(x, xbf, n4);
  }
  // 2) transpose+convert the 4 weight matrices (pds folded into wtp)
  {
    dim3 g(DMODEL / 32, DMODEL / 32, 4), b(32, 8);
    transpose_cvt_kernel<<<g, b, 0, stream>>>(Wq, Wk, Wv, Wp, pds,
                                              wtq, wtk, wtv, wtp);
  }
  // 3) fused QKV GEMM: grid (M/256, 3*5), XCD-chunk-swizzled
  {
    dim3 g(M_TOT / 256, 3 * NTC);
    gemm_bt_kernel<true><<<g, 512, 0, stream>>>(
        xbf, wtq, wtk, wtv, bq, bk, bv, (void*)qbf, (void*)kbf, (void*)vbf);
  }
  // 4) per-position attention, bf16 out over xbf
  attn_kernel<<<M_TOT, 256, 0, stream>>>(qbf, kbf, vbf, attnbf);
  // 5) output projection -> fp32 d_out (128x128 tiles, 2 blocks/CU)
  {
    dim3 g(M_TOT / 128, DMODEL / 128);
    gemm_bt128_kernel<<<g, 256, 0, stream>>>(attnbf, wtp, bp, out);
  }
}

// Round 9
// 306.178 us; speedup vs baseline: 1.1661x; 1.1661x over previous
//
#include <hip/hip_runtime.h>
#include <hip/hip_bf16.h>

// Problem constants (B=8,S=2048,H=16,D=80 -> DM=1280, M=B*S=16384)
#define M_TOT   16384
#define DMODEL  1280
#define NHEAD   16
#define DHEAD   80
#define NTC     5          // 1280 / 256 column tiles per matrix
#define BK      64
#define NKT     (DMODEL / BK)   // 20 K-tiles

typedef __attribute__((ext_vector_type(8))) __bf16 bf16x8;
typedef __attribute__((ext_vector_type(4))) float  f32x4;

__device__ __forceinline__ void gload16(const void* g, void* l) {
  __builtin_amdgcn_global_load_lds(
      (const __attribute__((address_space(1))) void*)g,
      (__attribute__((address_space(3))) void*)l, 16, 0, 0);
}

__device__ __forceinline__ float bf2f(unsigned short u) {
  return __uint_as_float((unsigned)u << 16);
}

// ---------------- fp32 -> bf16 convert, vectorized ----------------
__global__ __launch_bounds__(256) void cvt_bf16_kernel(
    const float* __restrict__ x, __hip_bfloat16* __restrict__ y, int n4) {
  int i = blockIdx.x * 256 + threadIdx.x;
  if (i >= n4) return;
  float4 v = ((const float4*)x)[i];
  union { ushort4 u; __hip_bfloat16 h[4]; } o;
  o.h[0] = __float2bfloat16(v.x);
  o.h[1] = __float2bfloat16(v.y);
  o.h[2] = __float2bfloat16(v.z);
  o.h[3] = __float2bfloat16(v.w);
  ((ushort4*)y)[i] = o.u;
}

// ---------------- W [K][N] fp32  ->  Wt [N][K] bf16 ----------------
// For Wp (z==3), per_dim_scale is folded in: Wt[n][k] = Wp[k][n]*pds[k%80].
__global__ __launch_bounds__(256) void transpose_cvt_kernel(
    const float* __restrict__ W0, const float* __restrict__ W1,
    const float* __restrict__ W2, const float* __restrict__ W3,
    const float* __restrict__ pds,
    __hip_bfloat16* __restrict__ T0, __hip_bfloat16* __restrict__ T1,
    __hip_bfloat16* __restrict__ T2, __hip_bfloat16* __restrict__ T3) {
  const float* W = blockIdx.z == 0 ? W0 : blockIdx.z == 1 ? W1
                 : blockIdx.z == 2 ? W2 : W3;
  __hip_bfloat16* T = blockIdx.z == 0 ? T0 : blockIdx.z == 1 ? T1
                    : blockIdx.z == 2 ? T2 : T3;
  __shared__ float tile[32][33];
  int bx = blockIdx.x * 32, by = blockIdx.y * 32;
  int tx = threadIdx.x, ty = threadIdx.y;   // block (32,8)
  for (int j = 0; j < 32; j += 8)
    tile[ty + j][tx] = W[(size_t)(by + ty + j) * DMODEL + bx + tx];
  __syncthreads();
  const float scale = (blockIdx.z == 3) ? pds[(by + tx) % DHEAD] : 1.0f;
  for (int j = 0; j < 32; j += 8)
    T[(size_t)(bx + ty + j) * DMODEL + by + tx] =
        __float2bfloat16(tile[tx][ty + j] * scale);
}

// 16-MFMA cluster: acc[MB..MB+3][0..3] += AF[j] x BF[n]
#define MFMA16(AF, BF, MB)                                                   \
  do {                                                                       \
    _Pragma("unroll")                                                        \
    for (int j_ = 0; j_ < 4; ++j_) {                                         \
      _Pragma("unroll")                                                      \
      for (int n_ = 0; n_ < 4; ++n_)                                         \
        acc[(MB) + j_][n_] = __builtin_amdgcn_mfma_f32_16x16x32_bf16(        \
            AF[j_], BF[n_], acc[(MB) + j_][n_], 0, 0, 0);                    \
    }                                                                        \
  } while (0)

// ---------------- QKV GEMM: 256x256, 8 waves ----------------
// NATURAL block mapping (R8 ERRATUM: chunked XCD swizzle tripled FETCH_SIZE.
// hw order b=x+64y gives XCD=x%8, so the 4 concurrent y-tiles sharing the
// same A rows co-locate on one XCD's L2 already — do not swizzle).
template <bool OUT_BF16>
__global__ __launch_bounds__(512, 2) void gemm_bt_kernel(
    const __hip_bfloat16* __restrict__ A,   // [M][K]
    const __hip_bfloat16* __restrict__ Bt0, // [N][K] (= W^T)
    const __hip_bfloat16* __restrict__ Bt1,
    const __hip_bfloat16* __restrict__ Bt2,
    const float* __restrict__ bias0, const float* __restrict__ bias1,
    const float* __restrict__ bias2,
    void* __restrict__ C0, void* __restrict__ C1, void* __restrict__ C2) {
  const int mat   = blockIdx.y / NTC;
  const int ntile = blockIdx.y % NTC;
  const __hip_bfloat16* Bt = mat == 0 ? Bt0 : mat == 1 ? Bt1 : Bt2;
  const float* bias        = mat == 0 ? bias0 : mat == 1 ? bias1 : bias2;
  void* C                  = mat == 0 ? C0 : mat == 1 ? C1 : C2;

  const int bm = blockIdx.x * 256;
  const int bn = ntile * 256;

  // A: 2 bufs x 2 ks x 16KB = 64KB at 0; B: same at 65536. Total 128KB.
  __shared__ __align__(16) char SLDS[131072];

  const int tid  = threadIdx.x;
  const int lane = tid & 63;
  const int wid  = tid >> 6;            // 0..7
  const int wm   = (wid >> 2) * 128;    // wave row offset: 0,128
  const int wn   = (wid & 3) * 64;      // wave col offset: 0,64,128,192
  const int lrow = lane & 15;
  const int l4   = lane >> 4;           // 0..3

  const int rsub  = lane >> 2;                        // 0..15
  const int cswz  = (lane & 3) ^ ((rsub >> 1) & 3);   // global chunk low bits
  const char* gsrc[2][2][2];
#pragma unroll
  for (int i = 0; i < 2; ++i) {
    const int rA = bm + wid * 32 + i * 16 + rsub;
    const int rB = bn + wid * 32 + i * 16 + rsub;
#pragma unroll
    for (int s = 0; s < 2; ++s) {
      gsrc[0][i][s] = (const char*)A  + (size_t)rA * (DMODEL * 2) + s * 64 + cswz * 16;
      gsrc[1][i][s] = (const char*)Bt + (size_t)rB * (DMODEL * 2) + s * 64 + cswz * 16;
    }
  }

  auto issueGroup = [&](int M, int s, int nbuf, size_t koff) {
    char* d = SLDS + M * 65536 + nbuf * 32768 + s * 16384 + wid * 2048;
    gload16(gsrc[M][0][s] + koff, d);
    gload16(gsrc[M][1][s] + koff, d + 1024);
  };

  f32x4 acc[8][4];
#pragma unroll
  for (int i = 0; i < 8; ++i)
#pragma unroll
    for (int j = 0; j < 4; ++j) acc[i][j] = (f32x4){0.f, 0.f, 0.f, 0.f};

  const int swz  = ((l4 ^ ((lrow >> 1) & 3)) << 4);
  const int aOff = (wm + lrow) * 64 + swz;           // within A region
  const int bOff = 65536 + (wn + lrow) * 64 + swz;   // within B region

  issueGroup(0, 0, 0, 0);   // A-ks0
  issueGroup(1, 0, 0, 0);   // B-ks0
  issueGroup(0, 1, 0, 0);   // A-ks1
  issueGroup(1, 1, 0, 0);   // B-ks1
  asm volatile("s_waitcnt vmcnt(4)" ::: "memory");
  __builtin_amdgcn_s_barrier();

  bf16x8 aFa[4], aFb[4], aFc[4], aFd[4], bF0[4], bF1[4];
#pragma unroll
  for (int j = 0; j < 4; ++j) aFa[j] = *(const bf16x8*)(const void*)(SLDS + aOff + j * 1024);
#pragma unroll
  for (int n = 0; n < 4; ++n) bF0[n] = *(const bf16x8*)(const void*)(SLDS + bOff + n * 1024);
  __builtin_amdgcn_sched_barrier(0);

  for (int t = 0; t < NKT; ++t) {
    const int buf = t & 1, nbuf = buf ^ 1;
    const int b0 = buf << 15;
    const int n0 = nbuf << 15;
    const size_t koff = (size_t)(t + 1) * (BK * 2);
    const bool pf = (t + 1 < NKT);

    // ---------- phase 0 ----------
    __builtin_amdgcn_s_barrier();
#pragma unroll
    for (int j = 0; j < 4; ++j)
      aFb[j] = *(const bf16x8*)(const void*)(SLDS + b0 + aOff + (4 + j) * 1024);
    if (pf) issueGroup(0, 0, nbuf, koff);
    __builtin_amdgcn_sched_barrier(0);
    __builtin_amdgcn_s_setprio(1);
    MFMA16(aFa, bF0, 0);
    __builtin_amdgcn_s_setprio(0);
    __builtin_amdgcn_sched_barrier(0);

    // ---------- phase 1 ----------
    if (pf) asm volatile("s_waitcnt vmcnt(2)" ::: "memory");
    else    asm volatile("s_waitcnt vmcnt(0)" ::: "memory");
    __builtin_amdgcn_s_barrier();
#pragma unroll
    for (int j = 0; j < 4; ++j)
      aFc[j] = *(const bf16x8*)(const void*)(SLDS + b0 + 16384 + aOff + j * 1024);
#pragma unroll
    for (int n = 0; n < 4; ++n)
      bF1[n] = *(const bf16x8*)(const void*)(SLDS + b0 + 16384 + bOff + n * 1024);
    if (pf) issueGroup(1, 0, nbuf, koff);
    __builtin_amdgcn_sched_barrier(0);
    __builtin_amdgcn_s_setprio(1);
    MFMA16(aFb, bF0, 4);
    __builtin_amdgcn_s_setprio(0);
    __builtin_amdgcn_sched_barrier(0);

    // ---------- phase 2 ----------
    __builtin_amdgcn_s_barrier();
#pragma unroll
    for (int j = 0; j < 4; ++j)
      aFd[j] = *(const bf16x8*)(const void*)(SLDS + b0 + 16384 + aOff + (4 + j) * 1024);
    if (pf) issueGroup(0, 1, nbuf, koff);
    __builtin_amdgcn_sched_barrier(0);
    __builtin_amdgcn_s_setprio(1);
    MFMA16(aFc, bF1, 0);
    __builtin_amdgcn_s_setprio(0);
    __builtin_amdgcn_sched_barrier(0);

    // ---------- phase 3 ----------
    if (pf) asm volatile("s_waitcnt vmcnt(2)" ::: "memory");
    __builtin_amdgcn_s_barrier();
    if (pf) {
#pragma unroll
      for (int j = 0; j < 4; ++j)
        aFa[j] = *(const bf16x8*)(const void*)(SLDS + n0 + aOff + j * 1024);
#pragma unroll
      for (int n = 0; n < 4; ++n)
        bF0[n] = *(const bf16x8*)(const void*)(SLDS + n0 + bOff + n * 1024);
      issueGroup(1, 1, nbuf, koff);
    }
    __builtin_amdgcn_sched_barrier(0);
    __builtin_amdgcn_s_setprio(1);
    MFMA16(aFd, bF1, 4);
    __builtin_amdgcn_s_setprio(0);
    __builtin_amdgcn_sched_barrier(0);
  }

  const int rbase = l4 * 4;
#pragma unroll
  for (int mi = 0; mi < 8; ++mi) {
#pragma unroll
    for (int ni = 0; ni < 4; ++ni) {
      const int col = bn + wn + ni * 16 + lrow;
      const float b2 = bias[col];
#pragma unroll
      for (int r = 0; r < 4; ++r) {
        const int row = bm + wm + mi * 16 + rbase + r;
        const float val = acc[mi][ni][r] + b2;
        if (OUT_BF16)
          ((__hip_bfloat16*)C)[(size_t)row * DMODEL + col] = __float2bfloat16(val);
        else
          ((float*)C)[(size_t)row * DMODEL + col] = val;
      }
    }
  }
}

// ---------------- proj GEMM: 128x128 tile, 4 waves, 2 blocks/CU ----------------
// Natural block mapping (see R8 erratum above).
__global__ __launch_bounds__(256, 2) void gemm_bt128_kernel(
    const __hip_bfloat16* __restrict__ A,   // [M][K]
    const __hip_bfloat16* __restrict__ Bt,  // [N][K]
    const float* __restrict__ bias,
    float* __restrict__ C) {
  const int bm = blockIdx.x * 128;
  const int bn = blockIdx.y * 128;

  // A: 2 bufs x 2 ks x 8KB = 32KB at 0; B: same at 32768. Total 64KB.
  __shared__ __align__(16) char SLDS[65536];

  const int tid  = threadIdx.x;
  const int lane = tid & 63;
  const int wid  = tid >> 6;            // 0..3
  const int wm   = (wid >> 1) * 64;     // wave row offset: 0,64
  const int wn   = (wid & 1) * 64;      // wave col offset: 0,64
  const int lrow = lane & 15;
  const int l4   = lane >> 4;

  const int rsub  = lane >> 2;
  const int cswz  = (lane & 3) ^ ((rsub >> 1) & 3);
  const char* gsrc[2][2][2];
#pragma unroll
  for (int i = 0; i < 2; ++i) {
    const int rA = bm + wid * 32 + i * 16 + rsub;
    const int rB = bn + wid * 32 + i * 16 + rsub;
#pragma unroll
    for (int s = 0; s < 2; ++s) {
      gsrc[0][i][s] = (const char*)A  + (size_t)rA * (DMODEL * 2) + s * 64 + cswz * 16;
      gsrc[1][i][s] = (const char*)Bt + (size_t)rB * (DMODEL * 2) + s * 64 + cswz * 16;
    }
  }

  auto issueGroup = [&](int M, int s, int nbuf, size_t koff) {
    char* d = SLDS + M * 32768 + nbuf * 16384 + s * 8192 + wid * 2048;
    gload16(gsrc[M][0][s] + koff, d);
    gload16(gsrc[M][1][s] + koff, d + 1024);
  };

  f32x4 acc[4][4];
#pragma unroll
  for (int i = 0; i < 4; ++i)
#pragma unroll
    for (int j = 0; j < 4; ++j) acc[i][j] = (f32x4){0.f, 0.f, 0.f, 0.f};

  const int swz  = ((l4 ^ ((lrow >> 1) & 3)) << 4);
  const int aOff = (wm + lrow) * 64 + swz;
  const int bOff = 32768 + (wn + lrow) * 64 + swz;

  issueGroup(0, 0, 0, 0);   // A-ks0
  issueGroup(1, 0, 0, 0);   // B-ks0
  issueGroup(0, 1, 0, 0);   // A-ks1
  issueGroup(1, 1, 0, 0);   // B-ks1

  for (int t = 0; t < NKT; ++t) {
    const int buf = t & 1, nbuf = buf ^ 1;
    const int b0 = buf << 14;            // 16KB per buf within each region
    const size_t koff = (size_t)(t + 1) * (BK * 2);
    const bool pf = (t + 1 < NKT);

    // ---------- phase 0: ks0 ----------
    asm volatile("s_waitcnt vmcnt(4)" ::: "memory");  // A-ks0,B-ks0(t) landed
    __builtin_amdgcn_s_barrier();
    bf16x8 aF[4], bF[4];
#pragma unroll
    for (int j = 0; j < 4; ++j)
      aF[j] = *(const bf16x8*)(const void*)(SLDS + b0 + aOff + j * 1024);
#pragma unroll
    for (int n = 0; n < 4; ++n)
      bF[n] = *(const bf16x8*)(const void*)(SLDS + b0 + bOff + n * 1024);
    if (pf) { issueGroup(0, 0, nbuf, koff); issueGroup(1, 0, nbuf, koff); }
    __builtin_amdgcn_sched_barrier(0);
    __builtin_amdgcn_s_setprio(1);
    MFMA16(aF, bF, 0);
    __builtin_amdgcn_s_setprio(0);
    __builtin_amdgcn_sched_barrier(0);

    // ---------- phase 1: ks1 ----------
    if (pf) asm volatile("s_waitcnt vmcnt(4)" ::: "memory");  // A-ks1,B-ks1(t)
    else    asm volatile("s_waitcnt vmcnt(0)" ::: "memory");
    __builtin_amdgcn_s_barrier();
#pragma unroll
    for (int j = 0; j < 4; ++j)
      aF[j] = *(const bf16x8*)(const void*)(SLDS + b0 + 8192 + aOff + j * 1024);
#pragma unroll
    for (int n = 0; n < 4; ++n)
      bF[n] = *(const bf16x8*)(const void*)(SLDS + b0 + 8192 + bOff + n * 1024);
    if (pf) { issueGroup(0, 1, nbuf, koff); issueGroup(1, 1, nbuf, koff); }
    __builtin_amdgcn_sched_barrier(0);
    __builtin_amdgcn_s_setprio(1);
    MFMA16(aF, bF, 0);
    __builtin_amdgcn_s_setprio(0);
    __builtin_amdgcn_sched_barrier(0);
  }

  const int rbase = l4 * 4;
#pragma unroll
  for (int mi = 0; mi < 4; ++mi) {
#pragma unroll
    for (int ni = 0; ni < 4; ++ni) {
      const int col = bn + wn + ni * 16 + lrow;
      const float bb = bias[col];
#pragma unroll
      for (int r = 0; r < 4; ++r) {
        const int row = bm + wm + mi * 16 + rbase + r;
        C[(size_t)row * DMODEL + col] = acc[mi][ni][r] + bb;
      }
    }
  }
}

// ---------------- per-position head-mixing attention ----------------
// scores[h][t] = (q[h,:] . k[t,:]) / sqrt(80) over heads (16x16), softmax
// over t, out[h][d] = sum_t p[h][t] v[t][d]. (per_dim_scale folded into Wp.)
// LDS rows padded to 84 floats (336B, 16B-aligned every row) so the staging
// conversions emit ds_write_b128 and QK/PV reads vectorize [R9].
__global__ __launch_bounds__(256) void attn_kernel(
    const __hip_bfloat16* __restrict__ q, const __hip_bfloat16* __restrict__ k,
    const __hip_bfloat16* __restrict__ v,
    __hip_bfloat16* __restrict__ out) {
  const size_t base = (size_t)blockIdx.x * DMODEL;
  __shared__ float qs[16][84], ks[16][84], vs[16][84];
  __shared__ float ps[16][17];
  const int tid = threadIdx.x;

  // 480 chunk loads (3 matrices x 160 bf16x8 chunks)
  for (int c = tid; c < 480; c += 256) {
    int matid = c / 160, idx = c - matid * 160;
    int h = idx / 10, d0 = (idx - h * 10) * 8;
    const __hip_bfloat16* src = matid == 0 ? q : matid == 1 ? k : v;
    union { bf16x8 v8; unsigned short u[8]; } uu;
    uu.v8 = *(const bf16x8*)(const void*)(src + base + (size_t)idx * 8);
    float* dst = (matid == 0 ? &qs[0][0] : matid == 1 ? &ks[0][0] : &vs[0][0]) +
                 h * 84 + d0;
#pragma unroll
    for (int j = 0; j < 8; ++j) dst[j] = bf2f(uu.u[j]);
  }
  __syncthreads();

  const int h = tid >> 4, t = tid & 15;
  float s = 0.f;
#pragma unroll
  for (int d = 0; d < DHEAD; ++d) s += qs[h][d] * ks[t][d];
  s *= 0.11180339887498948f;  // 1/sqrt(80)

  float m = s;
#pragma unroll
  for (int off = 8; off; off >>= 1) m = fmaxf(m, __shfl_xor(m, off, 16));
  float e = expf(s - m);
  float sum = e;
#pragma unroll
  for (int off = 8; off; off >>= 1) sum += __shfl_xor(sum, off, 16);
  ps[h][t] = e / sum;
  __syncthreads();

  // PV: 256 threads x 5 outputs (head hh = tid>>4, d = (tid&15)*5 .. +4)
  {
    const int hh   = tid >> 4;
    const int dloc = (tid & 15) * 5;
    float o[5];
#pragma unroll
    for (int j = 0; j < 5; ++j) o[j] = 0.f;
#pragma unroll
    for (int tt = 0; tt < 16; ++tt) {
      const float p = ps[hh][tt];
#pragma unroll
      for (int j = 0; j < 5; ++j) o[j] += p * vs[tt][dloc + j];
    }
    __hip_bfloat16* ob = out + base + (size_t)hh * DHEAD + dloc;
#pragma unroll
    for (int j = 0; j < 5; ++j) ob[j] = __float2bfloat16(o[j]);
  }
}

// ---------------- launch ----------------
extern "C" void kernel_launch(void* const* d_in, const int* in_sizes, int n_in,
                              void* d_out, int out_size, void* d_ws, size_t ws_size,
                              hipStream_t stream) {
  const float* x   = (const float*)d_in[0];
  const float* Wq  = (const float*)d_in[1];
  const float* bq  = (const float*)d_in[2];
  const float* Wk  = (const float*)d_in[3];
  const float* bk  = (const float*)d_in[4];
  const float* Wv  = (const float*)d_in[5];
  const float* bv  = (const float*)d_in[6];
  const float* Wp  = (const float*)d_in[7];
  const float* bp  = (const float*)d_in[8];
  const float* pds = (const float*)d_in[9];
  float* out = (float*)d_out;

  char* ws = (char*)d_ws;
  const size_t ACT = (size_t)M_TOT * DMODEL * 2;      // 41,943,040 B
  const size_t WT  = (size_t)DMODEL * DMODEL * 2;     //  3,276,800 B
  __hip_bfloat16* xbf = (__hip_bfloat16*)(ws);
  __hip_bfloat16* qbf = (__hip_bfloat16*)(ws + ACT);
  __hip_bfloat16* kbf = (__hip_bfloat16*)(ws + 2 * ACT);
  __hip_bfloat16* vbf = (__hip_bfloat16*)(ws + 3 * ACT);
  __hip_bfloat16* wtq = (__hip_bfloat16*)(ws + 4 * ACT);
  __hip_bfloat16* wtk = (__hip_bfloat16*)(ws + 4 * ACT + WT);
  __hip_bfloat16* wtv = (__hip_bfloat16*)(ws + 4 * ACT + 2 * WT);
  __hip_bfloat16* wtp = (__hip_bfloat16*)(ws + 4 * ACT + 3 * WT);
  __hip_bfloat16* attnbf = xbf;  // alias: x is dead after the QKV GEMM

  // 1) x -> bf16
  {
    int n4 = (M_TOT * DMODEL) / 4;  // 5,242,880
    cvt_bf16_kernel<<<n4 / 256, 256, 0, stream>>>(x, xbf, n4);
  }
  // 2) transpose+convert the 4 weight matrices (pds folded into wtp)
  {
    dim3 g(DMODEL / 32, DMODEL / 32, 4), b(32, 8);
    transpose_cvt_kernel<<<g, b, 0, stream>>>(Wq, Wk, Wv, Wp, pds,
                                              wtq, wtk, wtv, wtp);
  }
  // 3) fused QKV GEMM: grid (M/256, 3*5), natural mapping
  {
    dim3 g(M_TOT / 256, 3 * NTC);
    gemm_bt_kernel<true><<<g, 512, 0, stream>>>(
        xbf, wtq, wtk, wtv, bq, bk, bv, (void*)qbf, (void*)kbf, (void*)vbf);
  }
  // 4) per-position attention, bf16 out over xbf
  attn_kernel<<<M_TOT, 256, 0, stream>>>(qbf, kbf, vbf, attnbf);
  // 5) output projection -> fp32 d_out (128x128 tiles, 2 blocks/CU)
  {
    dim3 g(M_TOT / 128, DMODEL / 128);
    gemm_bt128_kernel<<<g, 256, 0, stream>>>(attnbf, wtp, bp, out);
  }
}